// Round 2
// baseline (7787.036 us; speedup 1.0000x reference)
//
#include <hip/hip_runtime.h>
#include <cstdint>
#include <cstddef>

#define N_TOK 8192
#define DIM   2048
#define VOC   32000
#define BT    128            // token rows per block
#define BV    128            // vocab cols per block
#define BKB   128            // K bytes (fp8 elems) per tile
#define NVT   (VOC / BV)     // 250 vocab tiles
#define NNT   (N_TOK / BT)   // 64 token tiles
#define KIT   (DIM / BKB)    // 16 K iterations
#define IGNORE_IDX (-100)

// prescale inputs by 2^6 at cast; both MX scales = 2^-6 (e8m0 byte 121)
// => dequant (64a * 2^-6)(64b * 2^-6) = a*b exactly.
#define PRESCALE 64.0f
#define SCALE_E8M0 0x79797979   // byte 121 replicated -> opsel-immune

typedef __attribute__((ext_vector_type(4))) int   i32x4;
typedef __attribute__((ext_vector_type(8))) int   i32x8;
typedef __attribute__((ext_vector_type(4))) float f32x4;

// ---------------------------------------------------------------------------
// Kernel 1: cast H and W to fp8 e4m3 (prescaled x64); zero the output.
// 8 floats -> 8 fp8 bytes per thread-iteration.
// ---------------------------------------------------------------------------
__global__ void cast_zero_kernel(const float* __restrict__ H, const float* __restrict__ W,
                                 unsigned char* __restrict__ Hb, unsigned char* __restrict__ Wb,
                                 float* __restrict__ out)
{
    if (blockIdx.x == 0 && threadIdx.x == 0) out[0] = 0.0f;
    const size_t nh = (size_t)N_TOK * DIM / 8;
    const size_t nw = (size_t)VOC * DIM / 8;
    size_t t = (size_t)blockIdx.x * blockDim.x + threadIdx.x;
    size_t stride = (size_t)gridDim.x * blockDim.x;
    const float4* H4 = (const float4*)H;
    const float4* W4 = (const float4*)W;
    int2* Hb8 = (int2*)Hb;
    int2* Wb8 = (int2*)Wb;
    for (size_t i = t; i < nh; i += stride) {
        float4 a = H4[2 * i], b = H4[2 * i + 1];
        int lo = __builtin_amdgcn_cvt_pk_fp8_f32(a.x * PRESCALE, a.y * PRESCALE, 0, false);
        lo     = __builtin_amdgcn_cvt_pk_fp8_f32(a.z * PRESCALE, a.w * PRESCALE, lo, true);
        int hi = __builtin_amdgcn_cvt_pk_fp8_f32(b.x * PRESCALE, b.y * PRESCALE, 0, false);
        hi     = __builtin_amdgcn_cvt_pk_fp8_f32(b.z * PRESCALE, b.w * PRESCALE, hi, true);
        Hb8[i] = make_int2(lo, hi);
    }
    for (size_t i = t; i < nw; i += stride) {
        float4 a = W4[2 * i], b = W4[2 * i + 1];
        int lo = __builtin_amdgcn_cvt_pk_fp8_f32(a.x * PRESCALE, a.y * PRESCALE, 0, false);
        lo     = __builtin_amdgcn_cvt_pk_fp8_f32(a.z * PRESCALE, a.w * PRESCALE, lo, true);
        int hi = __builtin_amdgcn_cvt_pk_fp8_f32(b.x * PRESCALE, b.y * PRESCALE, 0, false);
        hi     = __builtin_amdgcn_cvt_pk_fp8_f32(b.z * PRESCALE, b.w * PRESCALE, hi, true);
        Wb8[i] = make_int2(lo, hi);
    }
}

// ---------------------------------------------------------------------------
// Kernel 2: 128x128 MX-fp8 MFMA GEMM (logits = H · W^T), K=128 per MFMA,
// fused per-row (max, sum-exp) epilogue + target-logit extraction.
// Staging swizzle: global 16B-chunk index XORed with (row&7) so LDS stays
// linear (global_load_lds wave-uniform-base constraint) while fragment
// ds_read_b128s spread across all 32 banks.
// ---------------------------------------------------------------------------
#define GLOAD_LDS(gptr, lptr) __builtin_amdgcn_global_load_lds(                     \
        (const __attribute__((address_space(1))) void*)(gptr),                      \
        (__attribute__((address_space(3))) void*)(lptr), 16, 0, 0)

__global__ __launch_bounds__(256, 3)
void lmhead_gemm(const unsigned char* __restrict__ Hb,
                 const unsigned char* __restrict__ Wb,
                 const int* __restrict__ labels,
                 float* __restrict__ partMax,
                 float* __restrict__ partSum,
                 float* __restrict__ tgt)
{
    __shared__ unsigned char ldsA[BT * BKB];   // 16 KiB
    __shared__ unsigned char ldsB[BV * BKB];   // 16 KiB
    __shared__ float pm[2][BT];
    __shared__ float ps[2][BT];
    __shared__ int   ltgt[BT];

    // supergroup-of-8 swizzle for L2 locality
    int b = blockIdx.x;
    const int SG = 8;
    int group = b / (SG * NVT);
    int rem   = b % (SG * NVT);
    int vt    = rem / SG;
    int nt    = group * SG + (rem % SG);

    const int tid  = threadIdx.x;
    const int wave = tid >> 6;
    const int lane = tid & 63;
    const int wm   = wave >> 1;                // wave row (0..1) -> 64 token rows
    const int wn   = wave & 1;                 // wave col (0..1) -> 64 vocab cols
    const int l15  = lane & 15;
    const int q    = lane >> 4;                // 0..3 -> K chunk of 32

    const int rowBase = nt * BT;
    const int colBase = vt * BV;

    if (tid < BT) {
        int lb = labels[rowBase + tid];
        int lc = lb - colBase;
        ltgt[tid] = (lc >= 0 && lc < BV) ? lc : -1;
    }

    f32x4 acc[4][4];
#pragma unroll
    for (int i = 0; i < 4; ++i)
#pragma unroll
        for (int j = 0; j < 4; ++j)
            acc[i][j] = (f32x4){0.f, 0.f, 0.f, 0.f};

    // staging geometry: one inst = 64 lanes x 16B = 8 rows of 128B
    const int r8  = lane >> 3;                 // row within 8-row chunk
    const int c16 = lane & 7;                  // 16B slot within row
    const int gcol = ((c16 ^ r8) << 4);        // swizzled global 16B chunk

    // fragment ds_read swizzled offsets (row&7 == l15&7 since bases are x8)
    const int swz = l15 & 7;
    const int off0 = ((2 * q)     ^ swz) << 4;
    const int off1 = ((2 * q + 1) ^ swz) << 4;

    const unsigned char* gA = Hb + (size_t)rowBase * DIM;
    const unsigned char* gB = Wb + (size_t)colBase * DIM;

    for (int kt = 0; kt < KIT; ++kt) {
        const int k0 = kt * BKB;
#pragma unroll
        for (int s = 0; s < 4; ++s) {
            int chunk = s * 4 + wave;          // wave-uniform, 0..15
            int row   = chunk * 8 + r8;        // 0..127
            GLOAD_LDS(gA + (size_t)row * DIM + k0 + gcol, &ldsA[chunk * 8 * BKB]);
            GLOAD_LDS(gB + (size_t)row * DIM + k0 + gcol, &ldsB[chunk * 8 * BKB]);
        }
        __syncthreads();

        i32x8 af[4], bfr[4];
#pragma unroll
        for (int i = 0; i < 4; ++i) {
            int base = (wm * 64 + i * 16 + l15) * BKB;
            i32x4 lo = *(const i32x4*)&ldsA[base + off0];
            i32x4 hi = *(const i32x4*)&ldsA[base + off1];
            af[i] = __builtin_shufflevector(lo, hi, 0, 1, 2, 3, 4, 5, 6, 7);
        }
#pragma unroll
        for (int j = 0; j < 4; ++j) {
            int base = (wn * 64 + j * 16 + l15) * BKB;
            i32x4 lo = *(const i32x4*)&ldsB[base + off0];
            i32x4 hi = *(const i32x4*)&ldsB[base + off1];
            bfr[j] = __builtin_shufflevector(lo, hi, 0, 1, 2, 3, 4, 5, 6, 7);
        }

#pragma unroll
        for (int i = 0; i < 4; ++i)
#pragma unroll
            for (int j = 0; j < 4; ++j)
                acc[i][j] = __builtin_amdgcn_mfma_scale_f32_16x16x128_f8f6f4(
                    af[i], bfr[j], acc[i][j],
                    0 /*cbsz: A=fp8 e4m3*/, 0 /*blgp: B=fp8 e4m3*/,
                    0, SCALE_E8M0, 0, SCALE_E8M0);

        __syncthreads();
    }

    // ---- fused epilogue: per-row max & sum(exp) over this block's 128 cols ----
    // C/D layout (16x16): col = lane&15, row = (lane>>4)*4 + reg
#pragma unroll
    for (int i = 0; i < 4; ++i) {
#pragma unroll
        for (int r = 0; r < 4; ++r) {
            float v0 = acc[i][0][r], v1 = acc[i][1][r], v2 = acc[i][2][r], v3 = acc[i][3][r];
            float mx = fmaxf(fmaxf(v0, v1), fmaxf(v2, v3));
            mx = fmaxf(mx, __shfl_xor(mx, 1));
            mx = fmaxf(mx, __shfl_xor(mx, 2));
            mx = fmaxf(mx, __shfl_xor(mx, 4));
            mx = fmaxf(mx, __shfl_xor(mx, 8));
            float s = __expf(v0 - mx) + __expf(v1 - mx) + __expf(v2 - mx) + __expf(v3 - mx);
            s += __shfl_xor(s, 1);
            s += __shfl_xor(s, 2);
            s += __shfl_xor(s, 4);
            s += __shfl_xor(s, 8);
            int localRow = wm * 64 + i * 16 + q * 4 + r;
            if (l15 == 0) { pm[wn][localRow] = mx; ps[wn][localRow] = s; }
            int tc = ltgt[localRow];
            if (tc >= 0) {
#pragma unroll
                for (int j = 0; j < 4; ++j) {
                    if (wn * 64 + j * 16 + l15 == tc)
                        tgt[rowBase + localRow] = acc[i][j][r];
                }
            }
        }
    }
    __syncthreads();

    if (tid < BT) {
        float m0 = pm[0][tid], m1 = pm[1][tid];
        float M = fmaxf(m0, m1);
        float S = ps[0][tid] * __expf(m0 - M) + ps[1][tid] * __expf(m1 - M);
        size_t o = (size_t)vt * N_TOK + rowBase + tid;
        partMax[o] = M;
        partSum[o] = S;
    }
}

// ---------------------------------------------------------------------------
// Kernel 3: per-row online logsumexp over 250 tile-partials, NLL, global sum.
// ---------------------------------------------------------------------------
__global__ void reduce_kernel(const float* __restrict__ partMax,
                              const float* __restrict__ partSum,
                              const float* __restrict__ tgt,
                              const int* __restrict__ labels,
                              float* __restrict__ out)
{
    __shared__ float red[4];
    const int tid = threadIdx.x;
    const int n = blockIdx.x * blockDim.x + tid;

    float M = -1e30f, S = 0.f;
    for (int t = 0; t < NVT; ++t) {
        float m = partMax[(size_t)t * N_TOK + n];  // coalesced
        float s = partSum[(size_t)t * N_TOK + n];
        float nM = fmaxf(M, m);
        S = S * __expf(M - nM) + s * __expf(m - nM);
        M = nM;
    }
    int lb = labels[n];
    float nll = 0.f;
    if (lb != IGNORE_IDX) nll = __logf(S) + M - tgt[n];

    float v = nll;
    v += __shfl_xor(v, 32);
    v += __shfl_xor(v, 16);
    v += __shfl_xor(v, 8);
    v += __shfl_xor(v, 4);
    v += __shfl_xor(v, 2);
    v += __shfl_xor(v, 1);
    if ((tid & 63) == 0) red[tid >> 6] = v;
    __syncthreads();
    if (tid == 0) atomicAdd(out, red[0] + red[1] + red[2] + red[3]);
}

// ---------------------------------------------------------------------------
extern "C" void kernel_launch(void* const* d_in, const int* in_sizes, int n_in,
                              void* d_out, int out_size, void* d_ws, size_t ws_size,
                              hipStream_t stream)
{
    const float* H      = (const float*)d_in[0];   // [8192, 2048] fp32
    const int*   labels = (const int*)d_in[1];     // [8192] int32/int64->int per harness
    const float* W      = (const float*)d_in[2];   // [32000, 2048] fp32
    float* out = (float*)d_out;

    char* ws = (char*)d_ws;
    size_t need = (size_t)VOC * DIM + (size_t)N_TOK * DIM
                + 2 * (size_t)NVT * N_TOK * 4 + (size_t)N_TOK * 4;
    if (ws_size < need) return;

    unsigned char* Wb = (unsigned char*)ws;  ws += (size_t)VOC * DIM;    // 65.5 MB
    unsigned char* Hb = (unsigned char*)ws;  ws += (size_t)N_TOK * DIM;  // 16.8 MB
    float* partMax = (float*)ws;             ws += (size_t)NVT * N_TOK * 4;
    float* partSum = (float*)ws;             ws += (size_t)NVT * N_TOK * 4;
    float* tgt     = (float*)ws;

    cast_zero_kernel<<<4096, 256, 0, stream>>>(H, W, Hb, Wb, out);
    lmhead_gemm<<<NNT * NVT, 256, 0, stream>>>(Hb, Wb, labels, partMax, partSum, tgt);
    reduce_kernel<<<N_TOK / 256, 256, 0, stream>>>(partMax, partSum, tgt, labels, out);
}

// Round 3
// 6857.559 us; speedup vs baseline: 1.1355x; 1.1355x over previous
//
#include <hip/hip_runtime.h>
#include <cstdint>
#include <cstddef>

#define N_TOK 8192
#define DIM   2048
#define VOC   32000
#define BT    128            // token rows per block
#define BV    128            // vocab cols per block
#define BKB   128            // K bytes (fp8 elems) per tile
#define NVT   (VOC / BV)     // 250 vocab tiles
#define NNT   (N_TOK / BT)   // 64 token tiles
#define KIT   (DIM / BKB)    // 16 K iterations
#define IGNORE_IDX (-100)

// prescale inputs by 2^6 at cast; both MX scales = 2^-6 (e8m0 byte 121)
// => dequant (64a * 2^-6)(64b * 2^-6) = a*b exactly.
#define PRESCALE 64.0f
#define SCALE_E8M0 0x79797979   // byte 121 replicated -> opsel-immune

typedef __attribute__((ext_vector_type(4))) int   i32x4;
typedef __attribute__((ext_vector_type(8))) int   i32x8;
typedef __attribute__((ext_vector_type(4))) float f32x4;

// ---------------------------------------------------------------------------
// Kernel 1: cast H and W to fp8 e4m3 (prescaled x64); zero the output.
// ---------------------------------------------------------------------------
__global__ void cast_zero_kernel(const float* __restrict__ H, const float* __restrict__ W,
                                 unsigned char* __restrict__ Hb, unsigned char* __restrict__ Wb,
                                 float* __restrict__ out)
{
    if (blockIdx.x == 0 && threadIdx.x == 0) out[0] = 0.0f;
    const size_t nh = (size_t)N_TOK * DIM / 8;
    const size_t nw = (size_t)VOC * DIM / 8;
    size_t t = (size_t)blockIdx.x * blockDim.x + threadIdx.x;
    size_t stride = (size_t)gridDim.x * blockDim.x;
    const float4* H4 = (const float4*)H;
    const float4* W4 = (const float4*)W;
    int2* Hb8 = (int2*)Hb;
    int2* Wb8 = (int2*)Wb;
    for (size_t i = t; i < nh; i += stride) {
        float4 a = H4[2 * i], b = H4[2 * i + 1];
        int lo = __builtin_amdgcn_cvt_pk_fp8_f32(a.x * PRESCALE, a.y * PRESCALE, 0, false);
        lo     = __builtin_amdgcn_cvt_pk_fp8_f32(a.z * PRESCALE, a.w * PRESCALE, lo, true);
        int hi = __builtin_amdgcn_cvt_pk_fp8_f32(b.x * PRESCALE, b.y * PRESCALE, 0, false);
        hi     = __builtin_amdgcn_cvt_pk_fp8_f32(b.z * PRESCALE, b.w * PRESCALE, hi, true);
        Hb8[i] = make_int2(lo, hi);
    }
    for (size_t i = t; i < nw; i += stride) {
        float4 a = W4[2 * i], b = W4[2 * i + 1];
        int lo = __builtin_amdgcn_cvt_pk_fp8_f32(a.x * PRESCALE, a.y * PRESCALE, 0, false);
        lo     = __builtin_amdgcn_cvt_pk_fp8_f32(a.z * PRESCALE, a.w * PRESCALE, lo, true);
        int hi = __builtin_amdgcn_cvt_pk_fp8_f32(b.x * PRESCALE, b.y * PRESCALE, 0, false);
        hi     = __builtin_amdgcn_cvt_pk_fp8_f32(b.z * PRESCALE, b.w * PRESCALE, hi, true);
        Wb8[i] = make_int2(lo, hi);
    }
}

// ---------------------------------------------------------------------------
// Kernel 2: 128x128 MX-fp8 MFMA GEMM (logits = H · W^T), K=128 per MFMA.
// Register-pressure discipline (r2 spilled 24 GB of scratch):
//   - launch_bounds (256,2): 256-reg unified budget
//   - af[4] resident (32 regs), bfr streamed 1-at-a-time (16 regs w/ rotation)
// ---------------------------------------------------------------------------
#define GLOAD_LDS(gptr, lptr) __builtin_amdgcn_global_load_lds(                     \
        (const __attribute__((address_space(1))) void*)(gptr),                      \
        (__attribute__((address_space(3))) void*)(lptr), 16, 0, 0)

__device__ __forceinline__ i32x8 read_frag(const unsigned char* lds, int base, int off0, int off1)
{
    i32x4 lo = *(const i32x4*)&lds[base + off0];
    i32x4 hi = *(const i32x4*)&lds[base + off1];
    return __builtin_shufflevector(lo, hi, 0, 1, 2, 3, 4, 5, 6, 7);
}

__global__ __launch_bounds__(256, 2)
void lmhead_gemm(const unsigned char* __restrict__ Hb,
                 const unsigned char* __restrict__ Wb,
                 const int* __restrict__ labels,
                 float* __restrict__ partMax,
                 float* __restrict__ partSum,
                 float* __restrict__ tgt)
{
    __shared__ unsigned char ldsA[BT * BKB];   // 16 KiB
    __shared__ unsigned char ldsB[BV * BKB];   // 16 KiB
    __shared__ float pm[2][BT];
    __shared__ float ps[2][BT];
    __shared__ int   ltgt[BT];

    // supergroup-of-8 swizzle for L2 locality
    int b = blockIdx.x;
    const int SG = 8;
    int group = b / (SG * NVT);
    int rem   = b % (SG * NVT);
    int vt    = rem / SG;
    int nt    = group * SG + (rem % SG);

    const int tid  = threadIdx.x;
    const int wave = tid >> 6;
    const int lane = tid & 63;
    const int wm   = wave >> 1;                // wave row (0..1) -> 64 token rows
    const int wn   = wave & 1;                 // wave col (0..1) -> 64 vocab cols
    const int l15  = lane & 15;
    const int q    = lane >> 4;                // 0..3

    const int rowBase = nt * BT;
    const int colBase = vt * BV;

    if (tid < BT) {
        int lb = labels[rowBase + tid];
        int lc = lb - colBase;
        ltgt[tid] = (lc >= 0 && lc < BV) ? lc : -1;
    }

    f32x4 acc[4][4];
#pragma unroll
    for (int i = 0; i < 4; ++i)
#pragma unroll
        for (int j = 0; j < 4; ++j)
            acc[i][j] = (f32x4){0.f, 0.f, 0.f, 0.f};

    // staging geometry: one inst = 64 lanes x 16B = 8 rows of 128B
    const int r8  = lane >> 3;                 // row within 8-row chunk
    const int c16 = lane & 7;                  // 16B slot within row
    const int gcol = ((c16 ^ r8) << 4);        // swizzled global 16B chunk

    // fragment ds_read swizzled offsets
    const int swz = l15 & 7;
    const int off0 = ((2 * q)     ^ swz) << 4;
    const int off1 = ((2 * q + 1) ^ swz) << 4;

    const unsigned char* gA = Hb + (size_t)rowBase * DIM;
    const unsigned char* gB = Wb + (size_t)colBase * DIM;

    for (int kt = 0; kt < KIT; ++kt) {
        const int k0 = kt * BKB;
#pragma unroll
        for (int s = 0; s < 4; ++s) {
            int chunk = s * 4 + wave;          // wave-uniform, 0..15
            int row   = chunk * 8 + r8;        // 0..127
            GLOAD_LDS(gA + (size_t)row * DIM + k0 + gcol, &ldsA[chunk * 8 * BKB]);
            GLOAD_LDS(gB + (size_t)row * DIM + k0 + gcol, &ldsB[chunk * 8 * BKB]);
        }
        __syncthreads();

        i32x8 af[4];
#pragma unroll
        for (int i = 0; i < 4; ++i)
            af[i] = read_frag(ldsA, (wm * 64 + i * 16 + l15) * BKB, off0, off1);

        i32x8 bcur = read_frag(ldsB, (wn * 64 + 0 * 16 + l15) * BKB, off0, off1);
#pragma unroll
        for (int j = 0; j < 4; ++j) {
            i32x8 bnext = bcur;
            if (j < 3)
                bnext = read_frag(ldsB, (wn * 64 + (j + 1) * 16 + l15) * BKB, off0, off1);
#pragma unroll
            for (int i = 0; i < 4; ++i)
                acc[i][j] = __builtin_amdgcn_mfma_scale_f32_16x16x128_f8f6f4(
                    af[i], bcur, acc[i][j],
                    0 /*cbsz: A=fp8 e4m3*/, 0 /*blgp: B=fp8 e4m3*/,
                    0, SCALE_E8M0, 0, SCALE_E8M0);
            bcur = bnext;
        }

        __syncthreads();
    }

    // ---- fused epilogue: per-row max & sum(exp) over this block's 128 cols ----
    // C/D layout (16x16): col = lane&15, row = (lane>>4)*4 + reg
#pragma unroll
    for (int i = 0; i < 4; ++i) {
#pragma unroll
        for (int r = 0; r < 4; ++r) {
            float v0 = acc[i][0][r], v1 = acc[i][1][r], v2 = acc[i][2][r], v3 = acc[i][3][r];
            float mx = fmaxf(fmaxf(v0, v1), fmaxf(v2, v3));
            mx = fmaxf(mx, __shfl_xor(mx, 1));
            mx = fmaxf(mx, __shfl_xor(mx, 2));
            mx = fmaxf(mx, __shfl_xor(mx, 4));
            mx = fmaxf(mx, __shfl_xor(mx, 8));
            float s = __expf(v0 - mx) + __expf(v1 - mx) + __expf(v2 - mx) + __expf(v3 - mx);
            s += __shfl_xor(s, 1);
            s += __shfl_xor(s, 2);
            s += __shfl_xor(s, 4);
            s += __shfl_xor(s, 8);
            int localRow = wm * 64 + i * 16 + q * 4 + r;
            if (l15 == 0) { pm[wn][localRow] = mx; ps[wn][localRow] = s; }
            int tc = ltgt[localRow];
            if (tc >= 0) {
#pragma unroll
                for (int j = 0; j < 4; ++j) {
                    if (wn * 64 + j * 16 + l15 == tc)
                        tgt[rowBase + localRow] = acc[i][j][r];
                }
            }
        }
    }
    __syncthreads();

    if (tid < BT) {
        float m0 = pm[0][tid], m1 = pm[1][tid];
        float M = fmaxf(m0, m1);
        float S = ps[0][tid] * __expf(m0 - M) + ps[1][tid] * __expf(m1 - M);
        size_t o = (size_t)vt * N_TOK + rowBase + tid;
        partMax[o] = M;
        partSum[o] = S;
    }
}

// ---------------------------------------------------------------------------
// Kernel 3: per-row online logsumexp over 250 tile-partials, NLL, global sum.
// ---------------------------------------------------------------------------
__global__ void reduce_kernel(const float* __restrict__ partMax,
                              const float* __restrict__ partSum,
                              const float* __restrict__ tgt,
                              const int* __restrict__ labels,
                              float* __restrict__ out)
{
    __shared__ float red[4];
    const int tid = threadIdx.x;
    const int n = blockIdx.x * blockDim.x + tid;

    float M = -1e30f, S = 0.f;
    for (int t = 0; t < NVT; ++t) {
        float m = partMax[(size_t)t * N_TOK + n];  // coalesced
        float s = partSum[(size_t)t * N_TOK + n];
        float nM = fmaxf(M, m);
        S = S * __expf(M - nM) + s * __expf(m - nM);
        M = nM;
    }
    int lb = labels[n];
    float nll = 0.f;
    if (lb != IGNORE_IDX) nll = __logf(S) + M - tgt[n];

    float v = nll;
    v += __shfl_xor(v, 32);
    v += __shfl_xor(v, 16);
    v += __shfl_xor(v, 8);
    v += __shfl_xor(v, 4);
    v += __shfl_xor(v, 2);
    v += __shfl_xor(v, 1);
    if ((tid & 63) == 0) red[tid >> 6] = v;
    __syncthreads();
    if (tid == 0) atomicAdd(out, red[0] + red[1] + red[2] + red[3]);
}

// ---------------------------------------------------------------------------
extern "C" void kernel_launch(void* const* d_in, const int* in_sizes, int n_in,
                              void* d_out, int out_size, void* d_ws, size_t ws_size,
                              hipStream_t stream)
{
    const float* H      = (const float*)d_in[0];   // [8192, 2048] fp32
    const int*   labels = (const int*)d_in[1];     // [8192]
    const float* W      = (const float*)d_in[2];   // [32000, 2048] fp32
    float* out = (float*)d_out;

    char* ws = (char*)d_ws;
    size_t need = (size_t)VOC * DIM + (size_t)N_TOK * DIM
                + 2 * (size_t)NVT * N_TOK * 4 + (size_t)N_TOK * 4;
    if (ws_size < need) return;

    unsigned char* Wb = (unsigned char*)ws;  ws += (size_t)VOC * DIM;    // 65.5 MB
    unsigned char* Hb = (unsigned char*)ws;  ws += (size_t)N_TOK * DIM;  // 16.8 MB
    float* partMax = (float*)ws;             ws += (size_t)NVT * N_TOK * 4;
    float* partSum = (float*)ws;             ws += (size_t)NVT * N_TOK * 4;
    float* tgt     = (float*)ws;

    cast_zero_kernel<<<4096, 256, 0, stream>>>(H, W, Hb, Wb, out);
    lmhead_gemm<<<NNT * NVT, 256, 0, stream>>>(Hb, Wb, labels, partMax, partSum, tgt);
    reduce_kernel<<<N_TOK / 256, 256, 0, stream>>>(partMax, partSum, tgt, labels, out);
}

// Round 4
// 1267.880 us; speedup vs baseline: 6.1418x; 5.4087x over previous
//
#include <hip/hip_runtime.h>
#include <cstdint>
#include <cstddef>

#define N_TOK 8192
#define DIM   2048
#define VOC   32000
#define BT    128            // token rows per block
#define BV    128            // vocab cols per block
#define BKB   128            // K bytes (fp8 elems) per tile
#define NVT   (VOC / BV)     // 250 vocab tiles
#define NNT   (N_TOK / BT)   // 64 token tiles
#define KIT   (DIM / BKB)    // 16 K iterations
#define IGNORE_IDX (-100)

// prescale inputs by 2^6 at cast; both MX scales = 2^-6 (e8m0 byte 121)
// => dequant (64a * 2^-6)(64b * 2^-6) = a*b exactly.
#define PRESCALE 64.0f
#define SCALE_E8M0 0x79797979   // byte 121 replicated -> opsel-immune

typedef __attribute__((ext_vector_type(4)))  int   i32x4;
typedef __attribute__((ext_vector_type(8)))  int   i32x8;
typedef __attribute__((ext_vector_type(16))) float f32x16;

// ---------------------------------------------------------------------------
// Kernel 1: cast H and W to fp8 e4m3 (prescaled x64); zero the output.
// ---------------------------------------------------------------------------
__global__ void cast_zero_kernel(const float* __restrict__ H, const float* __restrict__ W,
                                 unsigned char* __restrict__ Hb, unsigned char* __restrict__ Wb,
                                 float* __restrict__ out)
{
    if (blockIdx.x == 0 && threadIdx.x == 0) out[0] = 0.0f;
    const size_t nh = (size_t)N_TOK * DIM / 8;
    const size_t nw = (size_t)VOC * DIM / 8;
    size_t t = (size_t)blockIdx.x * blockDim.x + threadIdx.x;
    size_t stride = (size_t)gridDim.x * blockDim.x;
    const float4* H4 = (const float4*)H;
    const float4* W4 = (const float4*)W;
    int2* Hb8 = (int2*)Hb;
    int2* Wb8 = (int2*)Wb;
    for (size_t i = t; i < nh; i += stride) {
        float4 a = H4[2 * i], b = H4[2 * i + 1];
        int lo = __builtin_amdgcn_cvt_pk_fp8_f32(a.x * PRESCALE, a.y * PRESCALE, 0, false);
        lo     = __builtin_amdgcn_cvt_pk_fp8_f32(a.z * PRESCALE, a.w * PRESCALE, lo, true);
        int hi = __builtin_amdgcn_cvt_pk_fp8_f32(b.x * PRESCALE, b.y * PRESCALE, 0, false);
        hi     = __builtin_amdgcn_cvt_pk_fp8_f32(b.z * PRESCALE, b.w * PRESCALE, hi, true);
        Hb8[i] = make_int2(lo, hi);
    }
    for (size_t i = t; i < nw; i += stride) {
        float4 a = W4[2 * i], b = W4[2 * i + 1];
        int lo = __builtin_amdgcn_cvt_pk_fp8_f32(a.x * PRESCALE, a.y * PRESCALE, 0, false);
        lo     = __builtin_amdgcn_cvt_pk_fp8_f32(a.z * PRESCALE, a.w * PRESCALE, lo, true);
        int hi = __builtin_amdgcn_cvt_pk_fp8_f32(b.x * PRESCALE, b.y * PRESCALE, 0, false);
        hi     = __builtin_amdgcn_cvt_pk_fp8_f32(b.z * PRESCALE, b.w * PRESCALE, hi, true);
        Wb8[i] = make_int2(lo, hi);
    }
}

// ---------------------------------------------------------------------------
// Kernel 2: 128x128 MX-fp8 GEMM using 32x32x64 scaled MFMA (logits = H · W^T).
// r3 post-mortem: 16x16x128 shape needed 64 regs of operands + 16 ds_read
// addrs -> arch-VGPR partition (half of unified budget) overflowed -> 10 GB
// scratch spill. 32x32x64 halves operand regs (4x8) and halves ds_reads.
// ---------------------------------------------------------------------------
#define GLOAD_LDS(gptr, lptr) __builtin_amdgcn_global_load_lds(                     \
        (const __attribute__((address_space(1))) void*)(gptr),                      \
        (__attribute__((address_space(3))) void*)(lptr), 16, 0, 0)

__device__ __forceinline__ i32x8 read_frag32(const unsigned char* lds, int rowbase, int c0, int swz)
{
    i32x4 lo = *(const i32x4*)&lds[rowbase + ((( c0     ) ^ swz) << 4)];
    i32x4 hi = *(const i32x4*)&lds[rowbase + (((c0 + 1) ^ swz) << 4)];
    return __builtin_shufflevector(lo, hi, 0, 1, 2, 3, 4, 5, 6, 7);
}

__global__ __launch_bounds__(256, 2)
void lmhead_gemm(const unsigned char* __restrict__ Hb,
                 const unsigned char* __restrict__ Wb,
                 const int* __restrict__ labels,
                 float* __restrict__ partMax,
                 float* __restrict__ partSum,
                 float* __restrict__ tgt)
{
    __shared__ unsigned char ldsA[BT * BKB];   // 16 KiB
    __shared__ unsigned char ldsB[BV * BKB];   // 16 KiB
    __shared__ float pm[2][BT];
    __shared__ float ps[2][BT];
    __shared__ int   ltgt[BT];

    // supergroup-of-8 swizzle for L2 locality
    int b = blockIdx.x;
    const int SG = 8;
    int group = b / (SG * NVT);
    int rem   = b % (SG * NVT);
    int vt    = rem / SG;
    int nt    = group * SG + (rem % SG);

    const int tid  = threadIdx.x;
    const int wave = tid >> 6;
    const int lane = tid & 63;
    const int wm   = wave >> 1;                // wave row (0..1) -> 64 token rows
    const int wn   = wave & 1;                 // wave col (0..1) -> 64 vocab cols
    const int l31  = lane & 31;
    const int half = lane >> 5;                // K-half within fragment

    const int rowBase = nt * BT;
    const int colBase = vt * BV;

    if (tid < BT) {
        int lb = labels[rowBase + tid];
        int lc = lb - colBase;
        ltgt[tid] = (lc >= 0 && lc < BV) ? lc : -1;
    }

    f32x16 acc[2][2];
#pragma unroll
    for (int i = 0; i < 2; ++i)
#pragma unroll
        for (int j = 0; j < 2; ++j)
            acc[i][j] = (f32x16){0.f,0.f,0.f,0.f,0.f,0.f,0.f,0.f,0.f,0.f,0.f,0.f,0.f,0.f,0.f,0.f};

    // staging geometry: one inst = 64 lanes x 16B = 8 rows of 128B
    const int r8   = lane >> 3;                // row within 8-row chunk
    const int c16  = lane & 7;                 // 16B slot within row
    const int gcol = ((c16 ^ r8) << 4);        // swizzled global 16B chunk

    // fragment ds_read: LDS row = tile row (stride 128B); 16B chunks XORed by row&7
    const int swz = lane & 7;                  // (tile row)&7 == lane&7 (bases %32==0)

    const unsigned char* gA = Hb + (size_t)rowBase * DIM;
    const unsigned char* gB = Wb + (size_t)colBase * DIM;

    const int arow0 = (wm * 64 +  0 + l31) * BKB;
    const int arow1 = (wm * 64 + 32 + l31) * BKB;
    const int brow0 = (wn * 64 +  0 + l31) * BKB;
    const int brow1 = (wn * 64 + 32 + l31) * BKB;

    for (int kt = 0; kt < KIT; ++kt) {
        const int k0 = kt * BKB;
#pragma unroll
        for (int s = 0; s < 4; ++s) {
            int chunk = s * 4 + wave;          // wave-uniform, 0..15
            int row   = chunk * 8 + r8;        // 0..127
            GLOAD_LDS(gA + (size_t)row * DIM + k0 + gcol, &ldsA[chunk * 8 * BKB]);
            GLOAD_LDS(gB + (size_t)row * DIM + k0 + gcol, &ldsB[chunk * 8 * BKB]);
        }
        __syncthreads();

#pragma unroll
        for (int kk = 0; kk < 2; ++kk) {
            const int cbase = kk * 4 + half * 2;   // 16B chunk index of this lane's 32 K-bytes
            i32x8 a0 = read_frag32(ldsA, arow0, cbase, swz);
            i32x8 a1 = read_frag32(ldsA, arow1, cbase, swz);
            i32x8 b0 = read_frag32(ldsB, brow0, cbase, swz);
            i32x8 b1 = read_frag32(ldsB, brow1, cbase, swz);
            acc[0][0] = __builtin_amdgcn_mfma_scale_f32_32x32x64_f8f6f4(
                a0, b0, acc[0][0], 0, 0, 0, SCALE_E8M0, 0, SCALE_E8M0);
            acc[0][1] = __builtin_amdgcn_mfma_scale_f32_32x32x64_f8f6f4(
                a0, b1, acc[0][1], 0, 0, 0, SCALE_E8M0, 0, SCALE_E8M0);
            acc[1][0] = __builtin_amdgcn_mfma_scale_f32_32x32x64_f8f6f4(
                a1, b0, acc[1][0], 0, 0, 0, SCALE_E8M0, 0, SCALE_E8M0);
            acc[1][1] = __builtin_amdgcn_mfma_scale_f32_32x32x64_f8f6f4(
                a1, b1, acc[1][1], 0, 0, 0, SCALE_E8M0, 0, SCALE_E8M0);
        }

        __syncthreads();
    }

    // ---- fused epilogue: per-row max & sum(exp) over this block's 128 cols ----
    // 32x32 C/D layout: col = lane&31, row = (reg&3) + 8*(reg>>2) + 4*(lane>>5)
#pragma unroll
    for (int i = 0; i < 2; ++i) {
#pragma unroll
        for (int r = 0; r < 16; ++r) {
            float v0 = acc[i][0][r], v1 = acc[i][1][r];
            float mx = fmaxf(v0, v1);
            mx = fmaxf(mx, __shfl_xor(mx, 1));
            mx = fmaxf(mx, __shfl_xor(mx, 2));
            mx = fmaxf(mx, __shfl_xor(mx, 4));
            mx = fmaxf(mx, __shfl_xor(mx, 8));
            mx = fmaxf(mx, __shfl_xor(mx, 16));
            float s = __expf(v0 - mx) + __expf(v1 - mx);
            s += __shfl_xor(s, 1);
            s += __shfl_xor(s, 2);
            s += __shfl_xor(s, 4);
            s += __shfl_xor(s, 8);
            s += __shfl_xor(s, 16);
            int localRow = wm * 64 + i * 32 + (r & 3) + 8 * (r >> 2) + 4 * half;
            if (l31 == 0) { pm[wn][localRow] = mx; ps[wn][localRow] = s; }
            int tc = ltgt[localRow];
            if (tc >= 0) {
#pragma unroll
                for (int j = 0; j < 2; ++j) {
                    if (wn * 64 + j * 32 + l31 == tc)
                        tgt[rowBase + localRow] = acc[i][j][r];
                }
            }
        }
    }
    __syncthreads();

    if (tid < BT) {
        float m0 = pm[0][tid], m1 = pm[1][tid];
        float M = fmaxf(m0, m1);
        float S = ps[0][tid] * __expf(m0 - M) + ps[1][tid] * __expf(m1 - M);
        size_t o = (size_t)vt * N_TOK + rowBase + tid;
        partMax[o] = M;
        partSum[o] = S;
    }
}

// ---------------------------------------------------------------------------
// Kernel 3: per-row online logsumexp over 250 tile-partials, NLL, global sum.
// ---------------------------------------------------------------------------
__global__ void reduce_kernel(const float* __restrict__ partMax,
                              const float* __restrict__ partSum,
                              const float* __restrict__ tgt,
                              const int* __restrict__ labels,
                              float* __restrict__ out)
{
    __shared__ float red[4];
    const int tid = threadIdx.x;
    const int n = blockIdx.x * blockDim.x + tid;

    float M = -1e30f, S = 0.f;
    for (int t = 0; t < NVT; ++t) {
        float m = partMax[(size_t)t * N_TOK + n];  // coalesced
        float s = partSum[(size_t)t * N_TOK + n];
        float nM = fmaxf(M, m);
        S = S * __expf(M - nM) + s * __expf(m - nM);
        M = nM;
    }
    int lb = labels[n];
    float nll = 0.f;
    if (lb != IGNORE_IDX) nll = __logf(S) + M - tgt[n];

    float v = nll;
    v += __shfl_xor(v, 32);
    v += __shfl_xor(v, 16);
    v += __shfl_xor(v, 8);
    v += __shfl_xor(v, 4);
    v += __shfl_xor(v, 2);
    v += __shfl_xor(v, 1);
    if ((tid & 63) == 0) red[tid >> 6] = v;
    __syncthreads();
    if (tid == 0) atomicAdd(out, red[0] + red[1] + red[2] + red[3]);
}

// ---------------------------------------------------------------------------
extern "C" void kernel_launch(void* const* d_in, const int* in_sizes, int n_in,
                              void* d_out, int out_size, void* d_ws, size_t ws_size,
                              hipStream_t stream)
{
    const float* H      = (const float*)d_in[0];   // [8192, 2048] fp32
    const int*   labels = (const int*)d_in[1];     // [8192]
    const float* W      = (const float*)d_in[2];   // [32000, 2048] fp32
    float* out = (float*)d_out;

    char* ws = (char*)d_ws;
    size_t need = (size_t)VOC * DIM + (size_t)N_TOK * DIM
                + 2 * (size_t)NVT * N_TOK * 4 + (size_t)N_TOK * 4;
    if (ws_size < need) return;

    unsigned char* Wb = (unsigned char*)ws;  ws += (size_t)VOC * DIM;    // 65.5 MB
    unsigned char* Hb = (unsigned char*)ws;  ws += (size_t)N_TOK * DIM;  // 16.8 MB
    float* partMax = (float*)ws;             ws += (size_t)NVT * N_TOK * 4;
    float* partSum = (float*)ws;             ws += (size_t)NVT * N_TOK * 4;
    float* tgt     = (float*)ws;

    cast_zero_kernel<<<4096, 256, 0, stream>>>(H, W, Hb, Wb, out);
    lmhead_gemm<<<NNT * NVT, 256, 0, stream>>>(Hb, Wb, labels, partMax, partSum, tgt);
    reduce_kernel<<<N_TOK / 256, 256, 0, stream>>>(partMax, partSum, tgt, labels, out);
}